// Round 1
// baseline (4389.685 us; speedup 1.0000x reference)
//
#include <hip/hip_runtime.h>
#include <hip/hip_fp16.h>

// HMM forward: B=64, T=1024, S=512, V=1024.
// Design: alpha'[j] = emis[obs_t][j] + m + log(sum_i exp(alpha[i]-m) * E[i,j])
// with E = exp(trans) precomputed in f16. One block per batch element,
// thread j owns state j. Inner loop = v_dot2_f32_f16 mat-vec.

constexpr int Bn = 64, Tn = 1024, Sn = 512, Vn = 1024;

typedef _Float16 half2_t __attribute__((ext_vector_type(2)));

__device__ __forceinline__ float dot2acc(unsigned int e, unsigned int p, float acc) {
#if __has_builtin(__builtin_amdgcn_fdot2)
    return __builtin_amdgcn_fdot2(__builtin_bit_cast(half2_t, e),
                                  __builtin_bit_cast(half2_t, p), acc, false);
#else
    __half2 eh = __builtin_bit_cast(__half2, e);
    __half2 qh = __builtin_bit_cast(__half2, p);
    float2 ef = __half22float2(eh), pf = __half22float2(qh);
    return acc + ef.x * pf.x + ef.y * pf.y;
#endif
}

// Pack E = exp(trans) as f16, layout Ep[(i>>3)*Sn + j][i&7] (8 halves = 16B per (i8,j))
__global__ void prep_E(const float* __restrict__ trans, __half* __restrict__ Ep) {
    int idx = blockIdx.x * blockDim.x + threadIdx.x;   // 0 .. Sn*Sn-1
    int i = idx >> 9;            // row (over states i), Sn=512
    int j = idx & (Sn - 1);      // col
    float e = __expf(trans[idx]);
    Ep[((((i >> 3) << 9) + j) << 3) + (i & 7)] = __float2half(e);
}

__global__ __launch_bounds__(512) void hmm_fwd(
    const int* __restrict__ obs,       // [B, T]
    const float* __restrict__ emis,    // [V, S]
    const float* __restrict__ prior,   // [S]
    const __half* __restrict__ Ep,     // packed exp(trans)
    float* __restrict__ out)           // [B]
{
    const int b = blockIdx.x;
    const int j = threadIdx.x;         // state index owned by this thread
    const int lane = j & 63, wv = j >> 6;   // 8 waves

    __shared__ int obs_s[Tn];
    __shared__ float red[8];
    __shared__ float red2[8];
    __shared__ __align__(16) __half ph[2][Sn];

    for (int k = j; k < Tn; k += Sn) obs_s[k] = obs[b * Tn + k];
    __syncthreads();

    float a = emis[obs_s[0] * Sn + j] + prior[j];

    const uint4* epv = reinterpret_cast<const uint4*>(Ep) + j;  // row stride Sn uint4s

    for (int t = 1; t < Tn; ++t) {
        // block max over alpha
        float m = a;
        #pragma unroll
        for (int off = 32; off; off >>= 1)
            m = fmaxf(m, __shfl_xor(m, off, 64));
        if (lane == 0) red[wv] = m;
        __syncthreads();
        #pragma unroll
        for (int w = 0; w < 8; ++w) m = fmaxf(m, red[w]);

        // P[i] = exp(alpha[i]-m) in f16 (double-buffered LDS)
        __half* P = ph[t & 1];
        P[j] = __float2half(__expf(a - m));
        __syncthreads();

        // acc = sum_i P[i] * E[i,j] via dot2
        const uint4* pv = reinterpret_cast<const uint4*>(ph[t & 1]);
        float acc = 0.f;
        #pragma unroll 8
        for (int i8 = 0; i8 < Sn / 8; ++i8) {
            uint4 e4 = epv[i8 * Sn];   // coalesced: lanes 16B apart
            uint4 p4 = pv[i8];         // LDS broadcast
            acc = dot2acc(e4.x, p4.x, acc);
            acc = dot2acc(e4.y, p4.y, acc);
            acc = dot2acc(e4.z, p4.z, acc);
            acc = dot2acc(e4.w, p4.w, acc);
        }

        a = emis[obs_s[t] * Sn + j] + m + __logf(acc);
    }

    // out[b] = logsumexp_j(alpha[j])
    float m = a;
    #pragma unroll
    for (int off = 32; off; off >>= 1)
        m = fmaxf(m, __shfl_xor(m, off, 64));
    if (lane == 0) red[wv] = m;
    __syncthreads();
    #pragma unroll
    for (int w = 0; w < 8; ++w) m = fmaxf(m, red[w]);

    float s = __expf(a - m);
    #pragma unroll
    for (int off = 32; off; off >>= 1)
        s += __shfl_xor(s, off, 64);
    if (lane == 0) red2[wv] = s;
    __syncthreads();
    float tot = 0.f;
    #pragma unroll
    for (int w = 0; w < 8; ++w) tot += red2[w];

    if (j == 0) out[b] = m + __logf(tot);
}

extern "C" void kernel_launch(void* const* d_in, const int* in_sizes, int n_in,
                              void* d_out, int out_size, void* d_ws, size_t ws_size,
                              hipStream_t stream) {
    const int*   obs   = (const int*)d_in[0];
    const float* emis  = (const float*)d_in[1];
    const float* trans = (const float*)d_in[2];
    const float* prior = (const float*)d_in[3];
    float* out = (float*)d_out;
    __half* Ep = (__half*)d_ws;   // 512*512*2B = 512 KB

    prep_E<<<(Sn * Sn) / 256, 256, 0, stream>>>(trans, Ep);
    hmm_fwd<<<Bn, Sn, 0, stream>>>(obs, emis, prior, Ep, out);
}

// Round 2
// 2022.614 us; speedup vs baseline: 2.1703x; 2.1703x over previous
//
#include <hip/hip_runtime.h>
#include <hip/hip_fp16.h>

// HMM forward, B=64, T=1024, S=512, V=1024.
// Grid 256 = 64 batches x 4 j-quarter blocks. E=exp(trans) lives in REGISTERS
// (64 half2/thread). Per-step alpha exchange among the 4 partner blocks via
// agent-scope atomics in d_ws (2-parity buffers + step-counter flags).

constexpr int Bn = 64, Tn = 1024, Sn = 512;
constexpr int JQ = 128;            // j columns per block
constexpr int ABUF_STRIDE = 544;   // f32 per (parity, b) slot: 512 + pad

typedef _Float16 half2_t __attribute__((ext_vector_type(2)));

__device__ __forceinline__ float dot2acc(half2_t e, half2_t p, float acc) {
    return __builtin_amdgcn_fdot2(e, p, acc, false);
}

__global__ __launch_bounds__(512) void hmm_fwd(
    const int* __restrict__ obs,       // [B, T]
    const float* __restrict__ emis,    // [V, S]
    const float* __restrict__ trans,   // [S, S]
    const float* __restrict__ prior,   // [S]
    float* __restrict__ abuf,          // [2][64][ABUF_STRIDE] f32
    int* __restrict__ flags,           // [64][4]
    float* __restrict__ out)           // [B]
{
    const int bx = blockIdx.x;
    const int b = bx & 63;
    const int q = bx >> 6;             // partners are bx = b + 64*q -> same XCD heuristic
    const int tid = threadIdx.x;
    const int j = tid & 127;           // column within quarter
    const int iq = tid >> 7;           // i-quarter handled by this thread
    const int jg = q * JQ + j;         // global column
    const int lane = tid & 63, wv = tid >> 6;

    __shared__ int obs_s[Tn];
    __shared__ __align__(16) _Float16 Pl[Sn];
    __shared__ float part[4 * 132];
    __shared__ float redm[8];
    __shared__ float reds[8];

    obs_s[tid] = obs[b * Tn + tid];
    obs_s[tid + 512] = obs[b * Tn + 512 + tid];

    // Load E slice into registers: Ereg[k] = (E[i0+2k][jg], E[i0+2k+1][jg])
    half2_t Ereg[64];
    const int i0 = iq * 128;
    #pragma unroll
    for (int k = 0; k < 64; ++k) {
        float e0 = __expf(trans[(i0 + 2 * k) * Sn + jg]);
        float e1 = __expf(trans[(i0 + 2 * k + 1) * Sn + jg]);
        Ereg[k] = half2_t{(_Float16)e0, (_Float16)e1};
    }
    __syncthreads();   // obs_s ready

    // alpha_0 (full vector, computed locally & identically by all partner blocks)
    float a_full = emis[obs_s[0] * Sn + tid] + prior[tid];
    float e_row = (tid < 128) ? emis[obs_s[1] * Sn + jg] : 0.f;

    float* bbase = abuf + (size_t)b * ABUF_STRIDE;
    int* flagp = flags + b * 4;

    for (int t = 1; t < Tn; ++t) {
        // ---- block max over alpha_{t-1}
        float m = a_full;
        #pragma unroll
        for (int off = 32; off; off >>= 1) m = fmaxf(m, __shfl_xor(m, off, 64));
        if (lane == 0) redm[wv] = m;
        __syncthreads();
        #pragma unroll
        for (int w = 0; w < 8; ++w) m = fmaxf(m, redm[w]);

        // ---- P = exp(alpha - m) into LDS (f16)
        Pl[tid] = (_Float16)__expf(a_full - m);
        __syncthreads();

        // ---- partial dot: thread (j, iq) sums its 128-i range from registers
        const uint4* Pv = (const uint4*)(Pl + i0);
        float acc = 0.f;
        #pragma unroll
        for (int k = 0; k < 16; ++k) {
            uint4 p4 = Pv[k];   // broadcast read (whole wave same address)
            acc = dot2acc(Ereg[4 * k + 0], __builtin_bit_cast(half2_t, p4.x), acc);
            acc = dot2acc(Ereg[4 * k + 1], __builtin_bit_cast(half2_t, p4.y), acc);
            acc = dot2acc(Ereg[4 * k + 2], __builtin_bit_cast(half2_t, p4.z), acc);
            acc = dot2acc(Ereg[4 * k + 3], __builtin_bit_cast(half2_t, p4.w), acc);
        }
        part[iq * 132 + j] = acc;
        __syncthreads();

        // ---- epilogue + publish own quarter (agent scope -> visible cross-XCD)
        float* slot = bbase + (size_t)(t & 1) * (64 * ABUF_STRIDE);
        if (tid < 128) {
            float s = part[j] + part[132 + j] + part[264 + j] + part[396 + j];
            float na = e_row + m + __logf(s);
            __hip_atomic_store(slot + q * JQ + j, na,
                               __ATOMIC_RELAXED, __HIP_MEMORY_SCOPE_AGENT);
        }
        __syncthreads();   // per-wave vmcnt drain: quarter globally visible
        if (tid == 0)
            __hip_atomic_store(flagp + q, t,
                               __ATOMIC_RELAXED, __HIP_MEMORY_SCOPE_AGENT);

        // ---- wait for the 3 partners, then read full alpha_t
        if (tid < 4 && tid != q) {
            while (__hip_atomic_load(flagp + tid,
                                     __ATOMIC_RELAXED, __HIP_MEMORY_SCOPE_AGENT) < t)
                __builtin_amdgcn_s_sleep(1);
        }
        __syncthreads();
        if (t < Tn - 1 && tid < 128)
            e_row = emis[obs_s[t + 1] * Sn + jg];   // prefetch next emission row
        a_full = __hip_atomic_load(slot + tid,
                                   __ATOMIC_RELAXED, __HIP_MEMORY_SCOPE_AGENT);
    }

    // ---- final logsumexp over alpha_{T-1}
    float m = a_full;
    #pragma unroll
    for (int off = 32; off; off >>= 1) m = fmaxf(m, __shfl_xor(m, off, 64));
    if (lane == 0) redm[wv] = m;
    __syncthreads();
    #pragma unroll
    for (int w = 0; w < 8; ++w) m = fmaxf(m, redm[w]);

    float s = __expf(a_full - m);
    #pragma unroll
    for (int off = 32; off; off >>= 1) s += __shfl_xor(s, off, 64);
    if (lane == 0) reds[wv] = s;
    __syncthreads();
    if (q == 0 && tid == 0) {
        float tot = 0.f;
        #pragma unroll
        for (int w = 0; w < 8; ++w) tot += reds[w];
        out[b] = m + __logf(tot);
    }
}

extern "C" void kernel_launch(void* const* d_in, const int* in_sizes, int n_in,
                              void* d_out, int out_size, void* d_ws, size_t ws_size,
                              hipStream_t stream) {
    const int*   obs   = (const int*)d_in[0];
    const float* emis  = (const float*)d_in[1];
    const float* trans = (const float*)d_in[2];
    const float* prior = (const float*)d_in[3];
    float* out = (float*)d_out;

    float* abuf = (float*)d_ws;                         // 2*64*544 f32 = 278528 B
    int* flags = (int*)((char*)d_ws + 2 * 64 * ABUF_STRIDE * sizeof(float));

    hipMemsetAsync(flags, 0, Bn * 4 * sizeof(int), stream);
    hmm_fwd<<<Bn * 4, 512, 0, stream>>>(obs, emis, trans, prior, abuf, flags, out);
}

// Round 3
// 1186.068 us; speedup vs baseline: 3.7010x; 1.7053x over previous
//
#include <hip/hip_runtime.h>

// HMM forward, B=64, T=1024, S=512, V=1024.
// Monolithic: one block per batch, thread j owns state j. E = exp(trans)
// quantized to i8 with per-row scales (folded into P's quantization), held
// entirely in registers (128 VGPRs of packed i8 column). Inner loop is
// v_dot4_i32_i8. NO inter-block communication.

constexpr int Bn = 64, Tn = 1024, Sn = 512;

__device__ __forceinline__ int dot4(unsigned int e, unsigned int p, int acc) {
#if __has_builtin(__builtin_amdgcn_sdot4)
    return __builtin_amdgcn_sdot4((int)e, (int)p, acc, false);
#elif __has_builtin(__builtin_amdgcn_udot4)
    return (int)__builtin_amdgcn_udot4(e, p, (unsigned)acc, false);
#else
    acc += (int)(e & 0xff) * (int)(p & 0xff);
    acc += (int)((e >> 8) & 0xff) * (int)((p >> 8) & 0xff);
    acc += (int)((e >> 16) & 0xff) * (int)((p >> 16) & 0xff);
    acc += (int)((e >> 24) & 0xff) * (int)((p >> 24) & 0xff);
    return acc;
#endif
}

// One block per row i. Compute rowmax_i, quantize row to u8 (0..127), store in
// dot4 layout: Eq[(i>>2)*2048 + j*4 + (i&3)], i.e. uint Eq_u[(i>>2)*512 + j].
__global__ __launch_bounds__(256) void prep_rows(
    const float* __restrict__ trans, unsigned char* __restrict__ Eq,
    float* __restrict__ rowmax)
{
    const int i = blockIdx.x;
    const int j = threadIdx.x;              // handles cols j and j+256
    const int lane = j & 63, wv = j >> 6;
    float t0 = trans[i * Sn + j];
    float t1 = trans[i * Sn + j + 256];
    float m = fmaxf(t0, t1);
    #pragma unroll
    for (int off = 32; off; off >>= 1) m = fmaxf(m, __shfl_xor(m, off, 64));
    __shared__ float rm[4];
    if (lane == 0) rm[wv] = m;
    __syncthreads();
    m = fmaxf(fmaxf(rm[0], rm[1]), fmaxf(rm[2], rm[3]));
    if (j == 0) rowmax[i] = m;
    int q0 = __float2int_rn(127.f * __expf(t0 - m));
    int q1 = __float2int_rn(127.f * __expf(t1 - m));
    Eq[(i >> 2) * 2048 + j * 4 + (i & 3)] = (unsigned char)q0;
    Eq[(i >> 2) * 2048 + (j + 256) * 4 + (i & 3)] = (unsigned char)q1;
}

// lr[i] = log2(127 * exp(rowmax_i - RM)); C = RM - 2*ln(127)
__global__ __launch_bounds__(512) void prep_scale(
    const float* __restrict__ rowmax, float* __restrict__ lr,
    float* __restrict__ Cp)
{
    const int i = threadIdx.x;
    const int lane = i & 63, wv = i >> 6;
    float m = rowmax[i];
    float rm = m;
    #pragma unroll
    for (int off = 32; off; off >>= 1) rm = fmaxf(rm, __shfl_xor(rm, off, 64));
    __shared__ float red[8];
    if (lane == 0) red[wv] = rm;
    __syncthreads();
    float RM = red[0];
    #pragma unroll
    for (int w = 1; w < 8; ++w) RM = fmaxf(RM, red[w]);
    lr[i] = (m - RM) * 1.44269504f + 6.98868469f;   // log2(127)=6.98868469
    if (i == 0) *Cp = RM - 9.68837417f;             // 2*ln(127)=9.68837417
}

__global__ __launch_bounds__(512) void hmm_fwd(
    const int* __restrict__ obs,        // [B, T]
    const float* __restrict__ emis,     // [V, S]
    const float* __restrict__ prior,    // [S]
    const unsigned int* __restrict__ Equ, // packed i8 E, uint view
    const float* __restrict__ lr,       // [S]
    const float* __restrict__ Cp,       // scalar
    float* __restrict__ out)            // [B]
{
    const int b = blockIdx.x;
    const int tid = threadIdx.x;        // state j owned by this thread
    const int lane = tid & 63, wv = tid >> 6;

    __shared__ int obs_s[Tn];
    __shared__ __align__(16) unsigned int Pb[2][Sn / 4];
    __shared__ float redm[8];
    __shared__ float reds[8];

    obs_s[tid] = obs[b * Tn + tid];
    obs_s[tid + 512] = obs[b * Tn + 512 + tid];

    // E column into registers: E[k] = rows 4k..4k+3, col tid
    unsigned int E[128];
    #pragma unroll
    for (int k = 0; k < 128; ++k) E[k] = Equ[k * Sn + tid];

    const float lr_t = lr[tid];
    const float C = *Cp;

    __syncthreads();   // obs_s ready

    float a = emis[obs_s[0] * Sn + tid] + prior[tid];
    float e_next = emis[obs_s[1] * Sn + tid];

    for (int t = 1; t < Tn; ++t) {
        // ---- exact block max of alpha
        float m = a;
        #pragma unroll
        for (int off = 32; off; off >>= 1) m = fmaxf(m, __shfl_xor(m, off, 64));
        if (lane == 0) redm[wv] = m;
        __syncthreads();                        // A: redm ready; prev-step P reads done
        #pragma unroll
        for (int w = 0; w < 8; ++w) m = fmaxf(m, redm[w]);

        // ---- quantize P: Gq = rn(exp2((a-m)*log2e + lr)) in 0..127
        int gi = __float2int_rn(exp2f(fmaf(a - m, 1.44269504f, lr_t)));
        ((unsigned char*)Pb[t & 1])[tid] = (unsigned char)gi;
        __syncthreads();                        // B: P ready

        float e_cur = e_next;
        if (t < Tn - 1) e_next = emis[obs_s[t + 1] * Sn + tid];  // hidden under dot

        // ---- idot = sum_i Gq[i] * Eq[i, tid] via dot4 (exact i32)
        const uint4* P4 = (const uint4*)Pb[t & 1];
        int idot = 0;
        #pragma unroll
        for (int kk = 0; kk < 32; ++kk) {
            uint4 p = P4[kk];                   // LDS broadcast
            idot = dot4(E[4 * kk + 0], p.x, idot);
            idot = dot4(E[4 * kk + 1], p.y, idot);
            idot = dot4(E[4 * kk + 2], p.z, idot);
            idot = dot4(E[4 * kk + 3], p.w, idot);
        }

        a = e_cur + m + C + __logf((float)idot);
    }

    // ---- out[b] = logsumexp_j(alpha[j])
    float m = a;
    #pragma unroll
    for (int off = 32; off; off >>= 1) m = fmaxf(m, __shfl_xor(m, off, 64));
    if (lane == 0) redm[wv] = m;
    __syncthreads();
    #pragma unroll
    for (int w = 0; w < 8; ++w) m = fmaxf(m, redm[w]);

    float s = __expf(a - m);
    #pragma unroll
    for (int off = 32; off; off >>= 1) s += __shfl_xor(s, off, 64);
    if (lane == 0) reds[wv] = s;
    __syncthreads();
    if (tid == 0) {
        float tot = 0.f;
        #pragma unroll
        for (int w = 0; w < 8; ++w) tot += reds[w];
        out[b] = m + __logf(tot);
    }
}

extern "C" void kernel_launch(void* const* d_in, const int* in_sizes, int n_in,
                              void* d_out, int out_size, void* d_ws, size_t ws_size,
                              hipStream_t stream) {
    const int*   obs   = (const int*)d_in[0];
    const float* emis  = (const float*)d_in[1];
    const float* trans = (const float*)d_in[2];
    const float* prior = (const float*)d_in[3];
    float* out = (float*)d_out;

    unsigned char* Eq = (unsigned char*)d_ws;                 // 256 KB
    float* rowmax = (float*)(Eq + Sn * Sn);                   // 2 KB
    float* lr     = rowmax + Sn;                              // 2 KB
    float* Cp     = lr + Sn;                                  // 4 B

    prep_rows<<<Sn, 256, 0, stream>>>(trans, Eq, rowmax);
    prep_scale<<<1, Sn, 0, stream>>>(rowmax, lr, Cp);
    hmm_fwd<<<Bn, Sn, 0, stream>>>(obs, emis, prior,
                                   (const unsigned int*)Eq, lr, Cp, out);
}

// Round 4
// 1129.574 us; speedup vs baseline: 3.8861x; 1.0500x over previous
//
#include <hip/hip_runtime.h>

// HMM forward, B=64, T=1024, S=512, V=1024.
// Monolithic: one block per batch, thread j owns state j. E = exp(trans)
// quantized to u8 (0..127) with per-row scales folded into P's quantization,
// held entirely in arch VGPRs (128 uints). Inner loop = v_dot4_i32_i8.
// Round 4 changes: __launch_bounds__(512,2) to prevent AGPR splitting of E,
// DPP-based wave max reduction (no ds_bpermute), tree cross-wave max.

constexpr int Bn = 64, Tn = 1024, Sn = 512;

__device__ __forceinline__ int dot4(unsigned int e, unsigned int p, int acc) {
#if __has_builtin(__builtin_amdgcn_sdot4)
    return __builtin_amdgcn_sdot4((int)e, (int)p, acc, false);
#elif __has_builtin(__builtin_amdgcn_udot4)
    return (int)__builtin_amdgcn_udot4(e, p, (unsigned)acc, false);
#else
    acc += (int)(e & 0xff) * (int)(p & 0xff);
    acc += (int)((e >> 8) & 0xff) * (int)((p >> 8) & 0xff);
    acc += (int)((e >> 16) & 0xff) * (int)((p >> 16) & 0xff);
    acc += (int)((e >> 24) & 0xff) * (int)((p >> 24) & 0xff);
    return acc;
#endif
}

#if __has_builtin(__builtin_amdgcn_update_dpp)
template <int CTRL>
__device__ __forceinline__ float dpp_fmax(float x) {
    int s = __builtin_bit_cast(int, x);
    int d = __builtin_amdgcn_update_dpp(s, s, CTRL, 0xf, 0xf, false);
    return fmaxf(x, __builtin_bit_cast(float, d));
}
// Full 64-lane max; returns wave-uniform value (via lane 63 readlane).
__device__ __forceinline__ float wave_max(float x) {
    x = dpp_fmax<0x121>(x);   // row_ror:1
    x = dpp_fmax<0x122>(x);   // row_ror:2
    x = dpp_fmax<0x124>(x);   // row_ror:4
    x = dpp_fmax<0x128>(x);   // row_ror:8 -> every lane has row-of-16 max
    x = dpp_fmax<0x142>(x);   // row_bcast:15
    x = dpp_fmax<0x143>(x);   // row_bcast:31 -> lanes 48..63 have wave max
    return __builtin_bit_cast(float,
        __builtin_amdgcn_readlane(__builtin_bit_cast(int, x), 63));
}
#else
__device__ __forceinline__ float wave_max(float x) {
    #pragma unroll
    for (int off = 32; off; off >>= 1) x = fmaxf(x, __shfl_xor(x, off, 64));
    return x;
}
#endif

// One block per row i. Compute rowmax_i, quantize row to u8 (0..127), store in
// dot4 layout: Eq[(i>>2)*2048 + j*4 + (i&3)], i.e. uint Eq_u[(i>>2)*512 + j].
__global__ __launch_bounds__(256) void prep_rows(
    const float* __restrict__ trans, unsigned char* __restrict__ Eq,
    float* __restrict__ rowmax)
{
    const int i = blockIdx.x;
    const int j = threadIdx.x;              // handles cols j and j+256
    const int lane = j & 63, wv = j >> 6;
    float t0 = trans[i * Sn + j];
    float t1 = trans[i * Sn + j + 256];
    float m = fmaxf(t0, t1);
    #pragma unroll
    for (int off = 32; off; off >>= 1) m = fmaxf(m, __shfl_xor(m, off, 64));
    __shared__ float rm[4];
    if (lane == 0) rm[wv] = m;
    __syncthreads();
    m = fmaxf(fmaxf(rm[0], rm[1]), fmaxf(rm[2], rm[3]));
    if (j == 0) rowmax[i] = m;
    int q0 = __float2int_rn(127.f * __expf(t0 - m));
    int q1 = __float2int_rn(127.f * __expf(t1 - m));
    Eq[(i >> 2) * 2048 + j * 4 + (i & 3)] = (unsigned char)q0;
    Eq[(i >> 2) * 2048 + (j + 256) * 4 + (i & 3)] = (unsigned char)q1;
}

// lr[i] = log2(127 * exp(rowmax_i - RM)); C = RM - 2*ln(127)
__global__ __launch_bounds__(512) void prep_scale(
    const float* __restrict__ rowmax, float* __restrict__ lr,
    float* __restrict__ Cp)
{
    const int i = threadIdx.x;
    const int lane = i & 63, wv = i >> 6;
    float m = rowmax[i];
    float rm = m;
    #pragma unroll
    for (int off = 32; off; off >>= 1) rm = fmaxf(rm, __shfl_xor(rm, off, 64));
    __shared__ float red[8];
    if (lane == 0) red[wv] = rm;
    __syncthreads();
    float RM = red[0];
    #pragma unroll
    for (int w = 1; w < 8; ++w) RM = fmaxf(RM, red[w]);
    lr[i] = (m - RM) * 1.44269504f + 6.98868469f;   // log2(127)=6.98868469
    if (i == 0) *Cp = RM - 9.68837417f;             // 2*ln(127)=9.68837417
}

__global__ __launch_bounds__(512, 2) void hmm_fwd(
    const int* __restrict__ obs,        // [B, T]
    const float* __restrict__ emis,     // [V, S]
    const float* __restrict__ prior,    // [S]
    const unsigned int* __restrict__ Equ, // packed u8 E, uint view
    const float* __restrict__ lr,       // [S]
    const float* __restrict__ Cp,       // scalar
    float* __restrict__ out)            // [B]
{
    const int b = blockIdx.x;
    const int tid = threadIdx.x;        // state j owned by this thread
    const int lane = tid & 63, wv = tid >> 6;

    __shared__ int obs_s[Tn];
    __shared__ __align__(16) unsigned int Pb[2][Sn / 4];
    __shared__ float redm[8];
    __shared__ float reds[8];

    obs_s[tid] = obs[b * Tn + tid];
    obs_s[tid + 512] = obs[b * Tn + 512 + tid];

    // E column into registers: E[k] = rows 4k..4k+3, col tid
    unsigned int E[128];
    #pragma unroll
    for (int k = 0; k < 128; ++k) E[k] = Equ[k * Sn + tid];

    const float lr_t = lr[tid];
    const float C = *Cp;

    __syncthreads();   // obs_s ready

    float a = emis[obs_s[0] * Sn + tid] + prior[tid];
    float e_next = emis[obs_s[1] * Sn + tid];

    for (int t = 1; t < Tn; ++t) {
        // ---- exact block max of alpha (DPP in-wave, LDS cross-wave)
        float mw = wave_max(a);
        if (lane == 0) redm[wv] = mw;
        __syncthreads();                        // A: redm ready
        float m = fmaxf(fmaxf(fmaxf(redm[0], redm[1]), fmaxf(redm[2], redm[3])),
                        fmaxf(fmaxf(redm[4], redm[5]), fmaxf(redm[6], redm[7])));

        // ---- quantize P: Gq = rn(exp2((a-m)*log2e + lr)) in 0..127
        int gi = __float2int_rn(exp2f(fmaf(a - m, 1.44269504f, lr_t)));
        ((unsigned char*)Pb[t & 1])[tid] = (unsigned char)gi;
        __syncthreads();                        // B: P ready

        float e_cur = e_next;
        if (t < Tn - 1) e_next = emis[obs_s[t + 1] * Sn + tid];  // hidden under dot

        // ---- idot = sum_i Gq[i] * Eq[i, tid] via dot4 (exact i32)
        const uint4* P4 = (const uint4*)Pb[t & 1];
        int idot = 0;
        #pragma unroll
        for (int kk = 0; kk < 32; ++kk) {
            uint4 p = P4[kk];                   // LDS broadcast
            idot = dot4(E[4 * kk + 0], p.x, idot);
            idot = dot4(E[4 * kk + 1], p.y, idot);
            idot = dot4(E[4 * kk + 2], p.z, idot);
            idot = dot4(E[4 * kk + 3], p.w, idot);
        }

        a = e_cur + m + C + __logf((float)idot);
    }

    // ---- out[b] = logsumexp_j(alpha[j]) (runs once; shuffle path is fine)
    float m = a;
    #pragma unroll
    for (int off = 32; off; off >>= 1) m = fmaxf(m, __shfl_xor(m, off, 64));
    if (lane == 0) redm[wv] = m;
    __syncthreads();
    #pragma unroll
    for (int w = 0; w < 8; ++w) m = fmaxf(m, redm[w]);

    float s = __expf(a - m);
    #pragma unroll
    for (int off = 32; off; off >>= 1) s += __shfl_xor(s, off, 64);
    if (lane == 0) reds[wv] = s;
    __syncthreads();
    if (tid == 0) {
        float tot = 0.f;
        #pragma unroll
        for (int w = 0; w < 8; ++w) tot += reds[w];
        out[b] = m + __logf(tot);
    }
}

extern "C" void kernel_launch(void* const* d_in, const int* in_sizes, int n_in,
                              void* d_out, int out_size, void* d_ws, size_t ws_size,
                              hipStream_t stream) {
    const int*   obs   = (const int*)d_in[0];
    const float* emis  = (const float*)d_in[1];
    const float* trans = (const float*)d_in[2];
    const float* prior = (const float*)d_in[3];
    float* out = (float*)d_out;

    unsigned char* Eq = (unsigned char*)d_ws;                 // 256 KB
    float* rowmax = (float*)(Eq + Sn * Sn);                   // 2 KB
    float* lr     = rowmax + Sn;                              // 2 KB
    float* Cp     = lr + Sn;                                  // 4 B

    prep_rows<<<Sn, 256, 0, stream>>>(trans, Eq, rowmax);
    prep_scale<<<1, Sn, 0, stream>>>(rowmax, lr, Cp);
    hmm_fwd<<<Bn, Sn, 0, stream>>>(obs, emis, prior,
                                   (const unsigned int*)Eq, lr, Cp, out);
}